// Round 1
// baseline (902.729 us; speedup 1.0000x reference)
//
#include <hip/hip_runtime.h>
#include <hip/hip_bf16.h>
#include <math.h>

// ---------------------------------------------------------------------------
// GAT 3-layer forward. Strategy:
//   per call: build CSR (dst-grouped) from edge_index (+self loops), then per
//   layer: f32 GEMM (h = x@W), per-node attention logits (al_s, al_d), then
//   per-dst-node softmax + weighted gather aggregation (no atomics).
// ---------------------------------------------------------------------------

#define NEG_SLOPE 0.2f
#define EPS_SM 1e-16f

__device__ __forceinline__ float wave_red_sum(float v) {
#pragma unroll
    for (int o = 32; o > 0; o >>= 1) v += __shfl_down(v, o, 64);
    return v;
}
__device__ __forceinline__ float wave_red_max(float v) {
#pragma unroll
    for (int o = 32; o > 0; o >>= 1) v = fmaxf(v, __shfl_down(v, o, 64));
    return v;
}

// ---------------- CSR build ----------------
__global__ void hist_kernel(const int* __restrict__ ei, int E, int N,
                            int* __restrict__ cnt) {
    int e = blockIdx.x * 256 + threadIdx.x;
    int ET = E + N;
    if (e >= ET) return;
    int dst = (e < E) ? ei[E + e] : (e - E);
    atomicAdd(&cnt[dst], 1);
}

__global__ void scan_block(const int* __restrict__ cnt, int n_cnt,
                           int* __restrict__ offs, int n_off,
                           int* __restrict__ bsums) {
    __shared__ int buf[1024];
    int gid = blockIdx.x * 1024 + threadIdx.x;
    int v = (gid < n_cnt) ? cnt[gid] : 0;
    buf[threadIdx.x] = v;
    __syncthreads();
#pragma unroll
    for (int off = 1; off < 1024; off <<= 1) {
        int t = (threadIdx.x >= off) ? buf[threadIdx.x - off] : 0;
        __syncthreads();
        buf[threadIdx.x] += t;
        __syncthreads();
    }
    if (gid < n_off) offs[gid] = buf[threadIdx.x] - v;  // exclusive within block
    if (threadIdx.x == 1023) bsums[blockIdx.x] = buf[1023];
}

__global__ void scan_sums(int* __restrict__ bsums, int nb) {
    if (threadIdx.x == 0 && blockIdx.x == 0) {
        int run = 0;
        for (int i = 0; i < nb; ++i) { int t = bsums[i]; bsums[i] = run; run += t; }
    }
}

__global__ void scan_add(int* __restrict__ offs, int n_off,
                         const int* __restrict__ bsums) {
    int gid = blockIdx.x * 1024 + threadIdx.x;
    if (gid < n_off) offs[gid] += bsums[blockIdx.x];
}

__global__ void fill_csr(const int* __restrict__ ei, int E, int N,
                         const int* __restrict__ offs, int* __restrict__ fil,
                         int* __restrict__ csr) {
    int e = blockIdx.x * 256 + threadIdx.x;
    int ET = E + N;
    if (e >= ET) return;
    int src, dst;
    if (e < E) { src = ei[e]; dst = ei[E + e]; }
    else       { src = dst = e - E; }
    int pos = offs[dst] + atomicAdd(&fil[dst], 1);
    csr[pos] = src;
}

// ---------------- f32 GEMM: C[M,N] = A[M,K] @ B[K,N] ----------------
// 64x64 tile, 4x4 micro-tile, TK=16
__global__ __launch_bounds__(256) void gemm_f32(
    const float* __restrict__ A, const float* __restrict__ B,
    float* __restrict__ C, int M, int N, int K) {
    __shared__ float As[16][68];  // [k][m], padded
    __shared__ float Bs[16][68];  // [k][n], padded
    const int bm = blockIdx.y * 64, bn = blockIdx.x * 64;
    const int tid = threadIdx.x;
    const int tx = tid & 15, ty = tid >> 4;
    const int la_m = tid >> 2, la_k = (tid & 3) * 4;
    const int lb_k = tid >> 4, lb_n = (tid & 15) * 4;
    float acc[4][4] = {};
    for (int k0 = 0; k0 < K; k0 += 16) {
        float4 av;
        if (bm + la_m < M)
            av = *(const float4*)(A + (size_t)(bm + la_m) * K + k0 + la_k);
        else
            av = make_float4(0.f, 0.f, 0.f, 0.f);
        float4 bv = *(const float4*)(B + (size_t)(k0 + lb_k) * N + bn + lb_n);
        As[la_k + 0][la_m] = av.x;
        As[la_k + 1][la_m] = av.y;
        As[la_k + 2][la_m] = av.z;
        As[la_k + 3][la_m] = av.w;
        *(float4*)&Bs[lb_k][lb_n] = bv;
        __syncthreads();
#pragma unroll
        for (int k = 0; k < 16; ++k) {
            float4 a4 = *(const float4*)&As[k][ty * 4];
            float4 b4 = *(const float4*)&Bs[k][tx * 4];
            float am[4] = {a4.x, a4.y, a4.z, a4.w};
            float bb[4] = {b4.x, b4.y, b4.z, b4.w};
#pragma unroll
            for (int i = 0; i < 4; ++i)
#pragma unroll
                for (int j = 0; j < 4; ++j) acc[i][j] += am[i] * bb[j];
        }
        __syncthreads();
    }
#pragma unroll
    for (int i = 0; i < 4; ++i) {
        int row = bm + ty * 4 + i;
        if (row < M) {
            float4 o = make_float4(acc[i][0], acc[i][1], acc[i][2], acc[i][3]);
            *(float4*)(C + (size_t)row * N + bn + tx * 4) = o;
        }
    }
}

// ---------------- attention logits: al_s/al_d [N,H] ----------------
template <int H, int C>
__global__ __launch_bounds__(64) void al_kernel(
    const float* __restrict__ h, const float* __restrict__ a_s,
    const float* __restrict__ a_d, float* __restrict__ als,
    float* __restrict__ ald) {
    int n = blockIdx.x;
    int lane = threadIdx.x;
#pragma unroll
    for (int hh = 0; hh < H; ++hh) {
        float ps = 0.f, pd = 0.f;
        for (int c = lane; c < C; c += 64) {
            float v = h[(size_t)n * (H * C) + hh * C + c];
            ps += v * a_s[hh * C + c];
            pd += v * a_d[hh * C + c];
        }
        ps = wave_red_sum(ps);
        pd = wave_red_sum(pd);
        if (lane == 0) { als[n * H + hh] = ps; ald[n * H + hh] = pd; }
    }
}

// ---------------- per-dst softmax + weighted aggregation ----------------
template <int H, int C, bool ACT>
__global__ __launch_bounds__(H * C) void aggregate_kernel(
    const float* __restrict__ h, const float* __restrict__ als,
    const float* __restrict__ ald, const int* __restrict__ offs,
    const int* __restrict__ csr, const float* __restrict__ bias,
    float* __restrict__ out) {
    const int n = blockIdx.x;
    const int tid = threadIdx.x;
    const int head = tid / C;
    const int base = offs[n];
    const int deg = offs[n + 1] - base;

    __shared__ float s_m[H], s_d[H];
    __shared__ float s_alpha[64 * H];
    __shared__ int s_src[64];

    // phase A: wave 0 computes per-head max and softmax denominator
    if (tid < 64) {
        float adv[H];
#pragma unroll
        for (int hh = 0; hh < H; ++hh) adv[hh] = ald[n * H + hh];
        float pm[H];
#pragma unroll
        for (int hh = 0; hh < H; ++hh) pm[hh] = -1e30f;
        for (int i = tid; i < deg; i += 64) {
            int s = csr[base + i];
#pragma unroll
            for (int hh = 0; hh < H; ++hh) {
                float sc = als[s * H + hh] + adv[hh];
                sc = (sc < 0.f) ? NEG_SLOPE * sc : sc;
                pm[hh] = fmaxf(pm[hh], sc);
            }
        }
#pragma unroll
        for (int hh = 0; hh < H; ++hh) {
            float m = wave_red_max(pm[hh]);
            pm[hh] = __shfl(m, 0, 64);
        }
        float ps[H];
#pragma unroll
        for (int hh = 0; hh < H; ++hh) ps[hh] = 0.f;
        for (int i = tid; i < deg; i += 64) {
            int s = csr[base + i];
#pragma unroll
            for (int hh = 0; hh < H; ++hh) {
                float sc = als[s * H + hh] + adv[hh];
                sc = (sc < 0.f) ? NEG_SLOPE * sc : sc;
                ps[hh] += expf(sc - pm[hh]);
            }
        }
#pragma unroll
        for (int hh = 0; hh < H; ++hh) {
            float d = wave_red_sum(ps[hh]);
            if (tid == 0) { s_m[hh] = pm[hh]; s_d[hh] = d + EPS_SM; }
        }
    }
    __syncthreads();

    float acc = 0.f;
    for (int c0 = 0; c0 < deg; c0 += 64) {
        int cl = min(64, deg - c0);
        if (tid < cl) {
            int s = csr[base + c0 + tid];
            s_src[tid] = s;
#pragma unroll
            for (int hh = 0; hh < H; ++hh) {
                float sc = als[s * H + hh] + ald[n * H + hh];
                sc = (sc < 0.f) ? NEG_SLOPE * sc : sc;
                s_alpha[tid * H + hh] = expf(sc - s_m[hh]) / s_d[hh];
            }
        }
        __syncthreads();
        for (int e = 0; e < cl; ++e) {
            acc += s_alpha[e * H + head] * h[(size_t)s_src[e] * (H * C) + tid];
        }
        __syncthreads();
    }
    float r = acc + bias[tid];
    if (ACT) r = (r > 0.f) ? r : expm1f(r);
    out[(size_t)n * (H * C) + tid] = r;
}

// ---------------------------------------------------------------------------
extern "C" void kernel_launch(void* const* d_in, const int* in_sizes, int n_in,
                              void* d_out, int out_size, void* d_ws,
                              size_t ws_size, hipStream_t stream) {
    const float* x   = (const float*)d_in[0];
    const int*   ei  = (const int*)d_in[1];
    const float* W1  = (const float*)d_in[2];
    const float* as1 = (const float*)d_in[3];
    const float* ad1 = (const float*)d_in[4];
    const float* b1  = (const float*)d_in[5];
    const float* W2  = (const float*)d_in[6];
    const float* as2 = (const float*)d_in[7];
    const float* ad2 = (const float*)d_in[8];
    const float* b2  = (const float*)d_in[9];
    const float* W3  = (const float*)d_in[10];
    const float* as3 = (const float*)d_in[11];
    const float* ad3 = (const float*)d_in[12];
    const float* b3  = (const float*)d_in[13];

    const int Nn = in_sizes[0] / 256;   // 50000 nodes
    const int E  = in_sizes[1] / 2;     // 800000 edges
    const int ET = E + Nn;              // + self loops

    // workspace carve
    char* p = (char*)d_ws;
    float* bufA = (float*)p; p += (size_t)Nn * 256 * 4;
    float* bufB = (float*)p; p += (size_t)Nn * 256 * 4;
    float* als  = (float*)p; p += (size_t)Nn * 4 * 4;
    float* ald  = (float*)p; p += (size_t)Nn * 4 * 4;
    int* cnt  = (int*)p; p += (size_t)Nn * 4;
    int* fil  = (int*)p; p += (size_t)Nn * 4;
    int* offs = (int*)p; p += (size_t)(Nn + 1) * 4;
    int* bsums = (int*)p; p += 256 * 4;
    int* csr  = (int*)p; p += (size_t)ET * 4;

    // --- CSR build ---
    hipMemsetAsync(cnt, 0, (size_t)2 * Nn * sizeof(int), stream);  // cnt + fil
    int nbE = (ET + 255) / 256;
    hist_kernel<<<nbE, 256, 0, stream>>>(ei, E, Nn, cnt);
    int nbS = (Nn + 1 + 1023) / 1024;
    scan_block<<<nbS, 1024, 0, stream>>>(cnt, Nn, offs, Nn + 1, bsums);
    scan_sums<<<1, 64, 0, stream>>>(bsums, nbS);
    scan_add<<<nbS, 1024, 0, stream>>>(offs, Nn + 1, bsums);
    fill_csr<<<nbE, 256, 0, stream>>>(ei, E, Nn, offs, fil, csr);

    int gm = (Nn + 63) / 64;

    // --- layer 1: 256 -> 256, H=4, C=64, ELU ---
    gemm_f32<<<dim3(4, gm), 256, 0, stream>>>(x, W1, bufA, Nn, 256, 256);
    al_kernel<4, 64><<<Nn, 64, 0, stream>>>(bufA, as1, ad1, als, ald);
    aggregate_kernel<4, 64, true>
        <<<Nn, 256, 0, stream>>>(bufA, als, ald, offs, csr, b1, bufB);

    // --- layer 2: 256 -> 256, H=4, C=64, ELU ---
    gemm_f32<<<dim3(4, gm), 256, 0, stream>>>(bufB, W2, bufA, Nn, 256, 256);
    al_kernel<4, 64><<<Nn, 64, 0, stream>>>(bufA, as2, ad2, als, ald);
    aggregate_kernel<4, 64, true>
        <<<Nn, 256, 0, stream>>>(bufA, als, ald, offs, csr, b2, bufB);

    // --- layer 3: 256 -> 128, H=1, C=128, no act ---
    gemm_f32<<<dim3(2, gm), 256, 0, stream>>>(bufB, W3, bufA, Nn, 128, 256);
    al_kernel<1, 128><<<Nn, 64, 0, stream>>>(bufA, as3, ad3, als, ald);
    aggregate_kernel<1, 128, false>
        <<<Nn, 128, 0, stream>>>(bufA, als, ald, offs, csr, b3, (float*)d_out);
}

// Round 2
// 852.969 us; speedup vs baseline: 1.0583x; 1.0583x over previous
//
#include <hip/hip_runtime.h>
#include <hip/hip_bf16.h>
#include <math.h>

// ---------------------------------------------------------------------------
// GAT 3-layer forward.
//   per call: build CSR (dst-grouped) from edge_index (+self loops), then per
//   layer: f32 GEMM (h = x@W), per-node attention logits (al_s, al_d), then
//   per-dst-node softmax + weighted gather aggregation (no atomics).
// R2: aggregate restructured — all-wave phase A (wave w = head w), exp cached
//   un-normalized in LDS for first 64 edges, final 1/denom scale, gather x4
//   unrolled for MLP.
// ---------------------------------------------------------------------------

#define NEG_SLOPE 0.2f
#define EPS_SM 1e-16f

__device__ __forceinline__ float wave_allred_sum(float v) {
#pragma unroll
    for (int o = 32; o > 0; o >>= 1) v += __shfl_xor(v, o, 64);
    return v;
}
__device__ __forceinline__ float wave_allred_max(float v) {
#pragma unroll
    for (int o = 32; o > 0; o >>= 1) v = fmaxf(v, __shfl_xor(v, o, 64));
    return v;
}

// ---------------- CSR build ----------------
__global__ void hist_kernel(const int* __restrict__ ei, int E, int N,
                            int* __restrict__ cnt) {
    int e = blockIdx.x * 256 + threadIdx.x;
    int ET = E + N;
    if (e >= ET) return;
    int dst = (e < E) ? ei[E + e] : (e - E);
    atomicAdd(&cnt[dst], 1);
}

__global__ void scan_block(const int* __restrict__ cnt, int n_cnt,
                           int* __restrict__ offs, int n_off,
                           int* __restrict__ bsums) {
    __shared__ int buf[1024];
    int gid = blockIdx.x * 1024 + threadIdx.x;
    int v = (gid < n_cnt) ? cnt[gid] : 0;
    buf[threadIdx.x] = v;
    __syncthreads();
#pragma unroll
    for (int off = 1; off < 1024; off <<= 1) {
        int t = (threadIdx.x >= off) ? buf[threadIdx.x - off] : 0;
        __syncthreads();
        buf[threadIdx.x] += t;
        __syncthreads();
    }
    if (gid < n_off) offs[gid] = buf[threadIdx.x] - v;  // exclusive within block
    if (threadIdx.x == 1023) bsums[blockIdx.x] = buf[1023];
}

__global__ void scan_sums(int* __restrict__ bsums, int nb) {
    if (threadIdx.x == 0 && blockIdx.x == 0) {
        int run = 0;
        for (int i = 0; i < nb; ++i) { int t = bsums[i]; bsums[i] = run; run += t; }
    }
}

__global__ void scan_add(int* __restrict__ offs, int n_off,
                         const int* __restrict__ bsums) {
    int gid = blockIdx.x * 1024 + threadIdx.x;
    if (gid < n_off) offs[gid] += bsums[blockIdx.x];
}

__global__ void fill_csr(const int* __restrict__ ei, int E, int N,
                         const int* __restrict__ offs, int* __restrict__ fil,
                         int* __restrict__ csr) {
    int e = blockIdx.x * 256 + threadIdx.x;
    int ET = E + N;
    if (e >= ET) return;
    int src, dst;
    if (e < E) { src = ei[e]; dst = ei[E + e]; }
    else       { src = dst = e - E; }
    int pos = offs[dst] + atomicAdd(&fil[dst], 1);
    csr[pos] = src;
}

// ---------------- f32 GEMM: C[M,N] = A[M,K] @ B[K,N] ----------------
__global__ __launch_bounds__(256) void gemm_f32(
    const float* __restrict__ A, const float* __restrict__ B,
    float* __restrict__ C, int M, int N, int K) {
    __shared__ float As[16][68];
    __shared__ float Bs[16][68];
    const int bm = blockIdx.y * 64, bn = blockIdx.x * 64;
    const int tid = threadIdx.x;
    const int tx = tid & 15, ty = tid >> 4;
    const int la_m = tid >> 2, la_k = (tid & 3) * 4;
    const int lb_k = tid >> 4, lb_n = (tid & 15) * 4;
    float acc[4][4] = {};
    for (int k0 = 0; k0 < K; k0 += 16) {
        float4 av;
        if (bm + la_m < M)
            av = *(const float4*)(A + (size_t)(bm + la_m) * K + k0 + la_k);
        else
            av = make_float4(0.f, 0.f, 0.f, 0.f);
        float4 bv = *(const float4*)(B + (size_t)(k0 + lb_k) * N + bn + lb_n);
        As[la_k + 0][la_m] = av.x;
        As[la_k + 1][la_m] = av.y;
        As[la_k + 2][la_m] = av.z;
        As[la_k + 3][la_m] = av.w;
        *(float4*)&Bs[lb_k][lb_n] = bv;
        __syncthreads();
#pragma unroll
        for (int k = 0; k < 16; ++k) {
            float4 a4 = *(const float4*)&As[k][ty * 4];
            float4 b4 = *(const float4*)&Bs[k][tx * 4];
            float am[4] = {a4.x, a4.y, a4.z, a4.w};
            float bb[4] = {b4.x, b4.y, b4.z, b4.w};
#pragma unroll
            for (int i = 0; i < 4; ++i)
#pragma unroll
                for (int j = 0; j < 4; ++j) acc[i][j] += am[i] * bb[j];
        }
        __syncthreads();
    }
#pragma unroll
    for (int i = 0; i < 4; ++i) {
        int row = bm + ty * 4 + i;
        if (row < M) {
            float4 o = make_float4(acc[i][0], acc[i][1], acc[i][2], acc[i][3]);
            *(float4*)(C + (size_t)row * N + bn + tx * 4) = o;
        }
    }
}

// ---------------- attention logits: al_s/al_d [N,H] ----------------
template <int H, int C>
__global__ __launch_bounds__(64) void al_kernel(
    const float* __restrict__ h, const float* __restrict__ a_s,
    const float* __restrict__ a_d, float* __restrict__ als,
    float* __restrict__ ald) {
    int n = blockIdx.x;
    int lane = threadIdx.x;
#pragma unroll
    for (int hh = 0; hh < H; ++hh) {
        float ps = 0.f, pd = 0.f;
        for (int c = lane; c < C; c += 64) {
            float v = h[(size_t)n * (H * C) + hh * C + c];
            ps += v * a_s[hh * C + c];
            pd += v * a_d[hh * C + c];
        }
        ps = wave_allred_sum(ps);
        pd = wave_allred_sum(pd);
        if (lane == 0) { als[n * H + hh] = ps; ald[n * H + hh] = pd; }
    }
}

// ---------------- aggregation, H=4 C=64 (256 threads, wave w = head w) -----
template <bool ACT>
__global__ __launch_bounds__(256) void aggregate_h4(
    const float* __restrict__ h, const float* __restrict__ als,
    const float* __restrict__ ald, const int* __restrict__ offs,
    const int* __restrict__ csr, const float* __restrict__ bias,
    float* __restrict__ out) {
    const int n = blockIdx.x;
    const int tid = threadIdx.x;
    const int w = tid >> 6;   // wave == head
    const int l = tid & 63;
    const int base = offs[n];
    const int deg = offs[n + 1] - base;

    __shared__ float s_alpha[4 * 64];   // un-normalized exp, [head][edge]
    __shared__ int s_src[64];

    const float ad_w = ald[n * 4 + w];

    // phase A pass 1: per-head max (wave w handles head w, all edges)
    float m = -1e30f;
    float sc0 = 0.f;  // cached score of this lane's first edge (i = l < 64)
    for (int i = l; i < deg; i += 64) {
        int s = csr[base + i];
        float sc = als[s * 4 + w] + ad_w;
        sc = (sc < 0.f) ? NEG_SLOPE * sc : sc;
        if (i < 64) sc0 = sc;
        m = fmaxf(m, sc);
    }
    m = wave_allred_max(m);

    // phase A pass 2: exp-sum; cache un-normalized exp of first 64 edges
    float ssum = 0.f;
    for (int i = l; i < deg; i += 64) {
        float sc;
        if (i < 64) sc = sc0;
        else {
            int s = csr[base + i];
            sc = als[s * 4 + w] + ad_w;
            sc = (sc < 0.f) ? NEG_SLOPE * sc : sc;
        }
        float ex = __expf(sc - m);
        if (i < 64) s_alpha[w * 64 + l] = ex;
        ssum += ex;
    }
    ssum = wave_allred_sum(ssum);
    const float rcpd = 1.f / (ssum + EPS_SM);

    // phase B: gather-FMA (un-normalized), scale once at the end
    float acc = 0.f;
    for (int c0 = 0; c0 < deg; c0 += 64) {
        const int cl = min(64, deg - c0);
        if (c0 == 0) {
            if (tid < cl) s_src[tid] = csr[base + tid];
        } else {
            __syncthreads();  // protect s_alpha / s_src reuse
            if (l < cl) {
                int s = csr[base + c0 + l];
                float sc = als[s * 4 + w] + ad_w;
                sc = (sc < 0.f) ? NEG_SLOPE * sc : sc;
                s_alpha[w * 64 + l] = __expf(sc - m);
                if (w == 0) s_src[l] = s;
            }
        }
        __syncthreads();
        int e = 0;
        for (; e + 4 <= cl; e += 4) {
            int s0 = s_src[e + 0], s1 = s_src[e + 1];
            int s2 = s_src[e + 2], s3 = s_src[e + 3];
            float a0 = s_alpha[w * 64 + e + 0], a1 = s_alpha[w * 64 + e + 1];
            float a2 = s_alpha[w * 64 + e + 2], a3 = s_alpha[w * 64 + e + 3];
            float v0 = h[(size_t)s0 * 256 + tid];
            float v1 = h[(size_t)s1 * 256 + tid];
            float v2 = h[(size_t)s2 * 256 + tid];
            float v3 = h[(size_t)s3 * 256 + tid];
            acc = fmaf(a0, v0, acc);
            acc = fmaf(a1, v1, acc);
            acc = fmaf(a2, v2, acc);
            acc = fmaf(a3, v3, acc);
        }
        for (; e < cl; ++e) {
            acc = fmaf(s_alpha[w * 64 + e], h[(size_t)s_src[e] * 256 + tid], acc);
        }
    }
    float r = acc * rcpd + bias[tid];
    if (ACT) r = (r > 0.f) ? r : expm1f(r);
    out[(size_t)n * 256 + tid] = r;
}

// ---------------- aggregation, H=1 C=128 (128 threads, 2 waves) ------------
__global__ __launch_bounds__(128) void aggregate_h1(
    const float* __restrict__ h, const float* __restrict__ als,
    const float* __restrict__ ald, const int* __restrict__ offs,
    const int* __restrict__ csr, const float* __restrict__ bias,
    float* __restrict__ out) {
    const int n = blockIdx.x;
    const int tid = threadIdx.x;
    const int w = tid >> 6;
    const int l = tid & 63;
    const int base = offs[n];
    const int deg = offs[n + 1] - base;

    __shared__ float s_alpha[128];  // un-normalized exp of first 128 edges
    __shared__ float s_red[2][2];
    __shared__ int s_src[64];

    const float ad_n = ald[n];

    // pass 1: max (waves split edges: edge = i*128 + w*64 + l)
    float m = -1e30f;
    float sc0 = 0.f;
    for (int i = w * 64 + l; i < deg; i += 128) {
        int s = csr[base + i];
        float sc = als[s] + ad_n;
        sc = (sc < 0.f) ? NEG_SLOPE * sc : sc;
        if (i < 128) sc0 = sc;
        m = fmaxf(m, sc);
    }
    m = wave_allred_max(m);
    if (l == 0) s_red[0][w] = m;
    __syncthreads();
    m = fmaxf(s_red[0][0], s_red[0][1]);

    // pass 2: exp-sum; cache first 128
    float ssum = 0.f;
    for (int i = w * 64 + l; i < deg; i += 128) {
        float sc;
        if (i < 128) sc = sc0;
        else {
            int s = csr[base + i];
            sc = als[s] + ad_n;
            sc = (sc < 0.f) ? NEG_SLOPE * sc : sc;
        }
        float ex = __expf(sc - m);
        if (i < 128) s_alpha[i] = ex;
        ssum += ex;
    }
    ssum = wave_allred_sum(ssum);
    if (l == 0) s_red[1][w] = ssum;
    __syncthreads();
    const float rcpd = 1.f / (s_red[1][0] + s_red[1][1] + EPS_SM);

    // phase B
    float acc = 0.f;
    for (int c0 = 0; c0 < deg; c0 += 64) {
        const int cl = min(64, deg - c0);
        if (c0 < 128) {
            __syncthreads();
            if (tid < cl) s_src[tid] = csr[base + c0 + tid];
        } else {
            __syncthreads();
            if (tid < cl) {
                int s = csr[base + c0 + tid];
                float sc = als[s] + ad_n;
                sc = (sc < 0.f) ? NEG_SLOPE * sc : sc;
                s_alpha[tid] = __expf(sc - m);
                s_src[tid] = s;
            }
        }
        __syncthreads();
        const float* ap = (c0 < 128) ? &s_alpha[c0] : &s_alpha[0];
        int e = 0;
        for (; e + 4 <= cl; e += 4) {
            int s0 = s_src[e + 0], s1 = s_src[e + 1];
            int s2 = s_src[e + 2], s3 = s_src[e + 3];
            float a0 = ap[e + 0], a1 = ap[e + 1];
            float a2 = ap[e + 2], a3 = ap[e + 3];
            float v0 = h[(size_t)s0 * 128 + tid];
            float v1 = h[(size_t)s1 * 128 + tid];
            float v2 = h[(size_t)s2 * 128 + tid];
            float v3 = h[(size_t)s3 * 128 + tid];
            acc = fmaf(a0, v0, acc);
            acc = fmaf(a1, v1, acc);
            acc = fmaf(a2, v2, acc);
            acc = fmaf(a3, v3, acc);
        }
        for (; e < cl; ++e) {
            acc = fmaf(ap[e], h[(size_t)s_src[e] * 128 + tid], acc);
        }
    }
    out[(size_t)n * 128 + tid] = acc * rcpd + bias[tid];
}

// ---------------------------------------------------------------------------
extern "C" void kernel_launch(void* const* d_in, const int* in_sizes, int n_in,
                              void* d_out, int out_size, void* d_ws,
                              size_t ws_size, hipStream_t stream) {
    const float* x   = (const float*)d_in[0];
    const int*   ei  = (const int*)d_in[1];
    const float* W1  = (const float*)d_in[2];
    const float* as1 = (const float*)d_in[3];
    const float* ad1 = (const float*)d_in[4];
    const float* b1  = (const float*)d_in[5];
    const float* W2  = (const float*)d_in[6];
    const float* as2 = (const float*)d_in[7];
    const float* ad2 = (const float*)d_in[8];
    const float* b2  = (const float*)d_in[9];
    const float* W3  = (const float*)d_in[10];
    const float* as3 = (const float*)d_in[11];
    const float* ad3 = (const float*)d_in[12];
    const float* b3  = (const float*)d_in[13];

    const int Nn = in_sizes[0] / 256;   // 50000 nodes
    const int E  = in_sizes[1] / 2;     // 800000 edges
    const int ET = E + Nn;              // + self loops

    // workspace carve
    char* p = (char*)d_ws;
    float* bufA = (float*)p; p += (size_t)Nn * 256 * 4;
    float* bufB = (float*)p; p += (size_t)Nn * 256 * 4;
    float* als  = (float*)p; p += (size_t)Nn * 4 * 4;
    float* ald  = (float*)p; p += (size_t)Nn * 4 * 4;
    int* cnt  = (int*)p; p += (size_t)Nn * 4;
    int* fil  = (int*)p; p += (size_t)Nn * 4;
    int* offs = (int*)p; p += (size_t)(Nn + 1) * 4;
    int* bsums = (int*)p; p += 256 * 4;
    int* csr  = (int*)p; p += (size_t)ET * 4;

    // --- CSR build ---
    hipMemsetAsync(cnt, 0, (size_t)2 * Nn * sizeof(int), stream);  // cnt + fil
    int nbE = (ET + 255) / 256;
    hist_kernel<<<nbE, 256, 0, stream>>>(ei, E, Nn, cnt);
    int nbS = (Nn + 1 + 1023) / 1024;
    scan_block<<<nbS, 1024, 0, stream>>>(cnt, Nn, offs, Nn + 1, bsums);
    scan_sums<<<1, 64, 0, stream>>>(bsums, nbS);
    scan_add<<<nbS, 1024, 0, stream>>>(offs, Nn + 1, bsums);
    fill_csr<<<nbE, 256, 0, stream>>>(ei, E, Nn, offs, fil, csr);

    int gm = (Nn + 63) / 64;

    // --- layer 1: 256 -> 256, H=4, C=64, ELU ---
    gemm_f32<<<dim3(4, gm), 256, 0, stream>>>(x, W1, bufA, Nn, 256, 256);
    al_kernel<4, 64><<<Nn, 64, 0, stream>>>(bufA, as1, ad1, als, ald);
    aggregate_h4<true><<<Nn, 256, 0, stream>>>(bufA, als, ald, offs, csr, b1, bufB);

    // --- layer 2: 256 -> 256, H=4, C=64, ELU ---
    gemm_f32<<<dim3(4, gm), 256, 0, stream>>>(bufB, W2, bufA, Nn, 256, 256);
    al_kernel<4, 64><<<Nn, 64, 0, stream>>>(bufA, as2, ad2, als, ald);
    aggregate_h4<true><<<Nn, 256, 0, stream>>>(bufA, als, ald, offs, csr, b2, bufB);

    // --- layer 3: 256 -> 128, H=1, C=128, no act ---
    gemm_f32<<<dim3(2, gm), 256, 0, stream>>>(bufB, W3, bufA, Nn, 128, 256);
    al_kernel<1, 128><<<Nn, 64, 0, stream>>>(bufA, as3, ad3, als, ald);
    aggregate_h1<<<Nn, 128, 0, stream>>>(bufA, als, ald, offs, csr, b3, (float*)d_out);
}

// Round 3
// 838.972 us; speedup vs baseline: 1.0760x; 1.0167x over previous
//
#include <hip/hip_runtime.h>
#include <hip/hip_bf16.h>
#include <math.h>

// ---------------------------------------------------------------------------
// GAT 3-layer forward.
// R3: (a) GEMM upgraded to 128x128 tile / 8x8 micro-tile (VALU-bound design),
//     (b) aggregation vectorized: one wave per dst node, float4 per lane,
//         no block barriers (wave-synchronous LDS), 4-deep gather MLP.
// ---------------------------------------------------------------------------

#define NEG_SLOPE 0.2f
#define EPS_SM 1e-16f

__device__ __forceinline__ float wave_allred_sum(float v) {
#pragma unroll
    for (int o = 32; o > 0; o >>= 1) v += __shfl_xor(v, o, 64);
    return v;
}
__device__ __forceinline__ float wave_allred_max(float v) {
#pragma unroll
    for (int o = 32; o > 0; o >>= 1) v = fmaxf(v, __shfl_xor(v, o, 64));
    return v;
}
__device__ __forceinline__ float4 lrelu4(float4 v) {
    v.x = (v.x < 0.f) ? NEG_SLOPE * v.x : v.x;
    v.y = (v.y < 0.f) ? NEG_SLOPE * v.y : v.y;
    v.z = (v.z < 0.f) ? NEG_SLOPE * v.z : v.z;
    v.w = (v.w < 0.f) ? NEG_SLOPE * v.w : v.w;
    return v;
}

// ---------------- CSR build ----------------
__global__ void hist_kernel(const int* __restrict__ ei, int E, int N,
                            int* __restrict__ cnt) {
    int e = blockIdx.x * 256 + threadIdx.x;
    int ET = E + N;
    if (e >= ET) return;
    int dst = (e < E) ? ei[E + e] : (e - E);
    atomicAdd(&cnt[dst], 1);
}

__global__ void scan_block(const int* __restrict__ cnt, int n_cnt,
                           int* __restrict__ offs, int n_off,
                           int* __restrict__ bsums) {
    __shared__ int buf[1024];
    int gid = blockIdx.x * 1024 + threadIdx.x;
    int v = (gid < n_cnt) ? cnt[gid] : 0;
    buf[threadIdx.x] = v;
    __syncthreads();
#pragma unroll
    for (int off = 1; off < 1024; off <<= 1) {
        int t = (threadIdx.x >= off) ? buf[threadIdx.x - off] : 0;
        __syncthreads();
        buf[threadIdx.x] += t;
        __syncthreads();
    }
    if (gid < n_off) offs[gid] = buf[threadIdx.x] - v;  // exclusive within block
    if (threadIdx.x == 1023) bsums[blockIdx.x] = buf[1023];
}

__global__ void scan_sums(int* __restrict__ bsums, int nb) {
    if (threadIdx.x == 0 && blockIdx.x == 0) {
        int run = 0;
        for (int i = 0; i < nb; ++i) { int t = bsums[i]; bsums[i] = run; run += t; }
    }
}

__global__ void scan_add(int* __restrict__ offs, int n_off,
                         const int* __restrict__ bsums) {
    int gid = blockIdx.x * 1024 + threadIdx.x;
    if (gid < n_off) offs[gid] += bsums[blockIdx.x];
}

__global__ void fill_csr(const int* __restrict__ ei, int E, int N,
                         const int* __restrict__ offs, int* __restrict__ fil,
                         int* __restrict__ csr) {
    int e = blockIdx.x * 256 + threadIdx.x;
    int ET = E + N;
    if (e >= ET) return;
    int src, dst;
    if (e < E) { src = ei[e]; dst = ei[E + e]; }
    else       { src = dst = e - E; }
    int pos = offs[dst] + atomicAdd(&fil[dst], 1);
    csr[pos] = src;
}

// ---------------- f32 GEMM: C[M,N] = A[M,K] @ B[K,N], 128x128, 8x8 micro ---
__global__ __launch_bounds__(256) void gemm_f32_128(
    const float* __restrict__ A, const float* __restrict__ B,
    float* __restrict__ C, int M, int N, int K) {
    __shared__ float As[16][132];  // [k][m], +4 pad
    __shared__ float Bs[16][132];  // [k][n], +4 pad
    const int bm = blockIdx.y * 128, bn = blockIdx.x * 128;
    const int tid = threadIdx.x;
    const int tx = tid & 15;   // col group 0..15
    const int ty = tid >> 4;   // row group 0..15
    const int la_k = (tid & 3) * 4;   // 0,4,8,12
    const int la_m = tid >> 2;        // 0..63 (+64 second pass)
    const int lb_k = tid >> 5;        // 0..7 (+8 second pass)
    const int lb_n = (tid & 31) * 4;  // 0..124

    float acc[8][8] = {};
    for (int k0 = 0; k0 < K; k0 += 16) {
        // stage A (128x16) transposed into [k][m]
#pragma unroll
        for (int p = 0; p < 2; ++p) {
            int row = bm + la_m + p * 64;
            float4 av = (row < M)
                ? *(const float4*)(A + (size_t)row * K + k0 + la_k)
                : make_float4(0.f, 0.f, 0.f, 0.f);
            As[la_k + 0][la_m + p * 64] = av.x;
            As[la_k + 1][la_m + p * 64] = av.y;
            As[la_k + 2][la_m + p * 64] = av.z;
            As[la_k + 3][la_m + p * 64] = av.w;
        }
        // stage B (16x128)
#pragma unroll
        for (int p = 0; p < 2; ++p) {
            float4 bv = *(const float4*)(B + (size_t)(k0 + lb_k + p * 8) * N + bn + lb_n);
            *(float4*)&Bs[lb_k + p * 8][lb_n] = bv;
        }
        __syncthreads();
#pragma unroll
        for (int k = 0; k < 16; ++k) {
            float4 a0 = *(const float4*)&As[k][ty * 8];
            float4 a1 = *(const float4*)&As[k][ty * 8 + 4];
            float4 b0 = *(const float4*)&Bs[k][tx * 8];
            float4 b1 = *(const float4*)&Bs[k][tx * 8 + 4];
            float am[8] = {a0.x, a0.y, a0.z, a0.w, a1.x, a1.y, a1.z, a1.w};
            float bb[8] = {b0.x, b0.y, b0.z, b0.w, b1.x, b1.y, b1.z, b1.w};
#pragma unroll
            for (int i = 0; i < 8; ++i)
#pragma unroll
                for (int j = 0; j < 8; ++j) acc[i][j] = fmaf(am[i], bb[j], acc[i][j]);
        }
        __syncthreads();
    }
#pragma unroll
    for (int i = 0; i < 8; ++i) {
        int row = bm + ty * 8 + i;
        if (row < M) {
            float4 o0 = make_float4(acc[i][0], acc[i][1], acc[i][2], acc[i][3]);
            float4 o1 = make_float4(acc[i][4], acc[i][5], acc[i][6], acc[i][7]);
            *(float4*)(C + (size_t)row * N + bn + tx * 8) = o0;
            *(float4*)(C + (size_t)row * N + bn + tx * 8 + 4) = o1;
        }
    }
}

// ---------------- attention logits: al_s/al_d [N,H] ----------------
template <int H, int C>
__global__ __launch_bounds__(64) void al_kernel(
    const float* __restrict__ h, const float* __restrict__ a_s,
    const float* __restrict__ a_d, float* __restrict__ als,
    float* __restrict__ ald) {
    int n = blockIdx.x;
    int lane = threadIdx.x;
#pragma unroll
    for (int hh = 0; hh < H; ++hh) {
        float ps = 0.f, pd = 0.f;
        for (int c = lane; c < C; c += 64) {
            float v = h[(size_t)n * (H * C) + hh * C + c];
            ps += v * a_s[hh * C + c];
            pd += v * a_d[hh * C + c];
        }
        ps = wave_allred_sum(ps);
        pd = wave_allred_sum(pd);
        if (lane == 0) { als[n * H + hh] = ps; ald[n * H + hh] = pd; }
    }
}

// ---------------- aggregation H=4 C=64: 1 wave / node, float4 / lane -------
template <bool ACT>
__global__ __launch_bounds__(256) void aggregate_h4_v2(
    const float* __restrict__ h, const float4* __restrict__ als4,
    const float4* __restrict__ ald4, const int* __restrict__ offs,
    const int* __restrict__ csr, const float* __restrict__ bias,
    float* __restrict__ out, int Nn) {
    const int tid = threadIdx.x;
    const int w = tid >> 6;           // wave in block
    const int l = tid & 63;           // lane
    const int n = blockIdx.x * 4 + w; // one node per wave
    __shared__ float s_alpha[4][64][4];
    __shared__ int s_src[4][64];
    if (n >= Nn) return;

    const int base = offs[n];
    const int deg = offs[n + 1] - base;
    const float4 adv = ald4[n];

    // ---- phase A pass 1: per-head max over edges (lane l owns edge l,l+64..)
    const bool has0 = (l < deg);
    int src0 = 0;
    float4 sc0 = make_float4(-1e30f, -1e30f, -1e30f, -1e30f);
    if (has0) {
        src0 = csr[base + l];
        float4 a = als4[src0];
        sc0 = lrelu4(make_float4(a.x + adv.x, a.y + adv.y, a.z + adv.z, a.w + adv.w));
    }
    float4 m = sc0;
    for (int i = l + 64; i < deg; i += 64) {
        int s = csr[base + i];
        float4 a = als4[s];
        float4 sc = lrelu4(make_float4(a.x + adv.x, a.y + adv.y, a.z + adv.z, a.w + adv.w));
        m.x = fmaxf(m.x, sc.x); m.y = fmaxf(m.y, sc.y);
        m.z = fmaxf(m.z, sc.z); m.w = fmaxf(m.w, sc.w);
    }
    m.x = wave_allred_max(m.x); m.y = wave_allred_max(m.y);
    m.z = wave_allred_max(m.z); m.w = wave_allred_max(m.w);

    // ---- phase A pass 2: exp-sum; cache un-normalized exp of first 64 edges
    float4 ssum = make_float4(0.f, 0.f, 0.f, 0.f);
    if (has0) {
        float4 ex = make_float4(__expf(sc0.x - m.x), __expf(sc0.y - m.y),
                                __expf(sc0.z - m.z), __expf(sc0.w - m.w));
        *(float4*)&s_alpha[w][l][0] = ex;
        s_src[w][l] = src0;
        ssum = ex;
    }
    for (int i = l + 64; i < deg; i += 64) {
        int s = csr[base + i];
        float4 a = als4[s];
        float4 sc = lrelu4(make_float4(a.x + adv.x, a.y + adv.y, a.z + adv.z, a.w + adv.w));
        ssum.x += __expf(sc.x - m.x); ssum.y += __expf(sc.y - m.y);
        ssum.z += __expf(sc.z - m.z); ssum.w += __expf(sc.w - m.w);
    }
    ssum.x = wave_allred_sum(ssum.x); ssum.y = wave_allred_sum(ssum.y);
    ssum.z = wave_allred_sum(ssum.z); ssum.w = wave_allred_sum(ssum.w);

    const int head = l >> 4;  // this lane's 4 channels (4l..4l+3) share a head
    float rc;
    {
        float d = (head == 0) ? ssum.x : (head == 1) ? ssum.y
                 : (head == 2) ? ssum.z : ssum.w;
        rc = 1.f / (d + EPS_SM);
    }

    // ---- phase B: gather full rows, one wave per edge-row, 4 floats/lane
    float4 acc = make_float4(0.f, 0.f, 0.f, 0.f);
    for (int c0 = 0; c0 < deg; c0 += 64) {
        const int cl = min(64, deg - c0);
        if (c0 > 0) {
            // refill alpha/src (wave-synchronous: no barrier needed)
            if (l < cl) {
                int s = csr[base + c0 + l];
                float4 a = als4[s];
                float4 sc = lrelu4(make_float4(a.x + adv.x, a.y + adv.y,
                                               a.z + adv.z, a.w + adv.w));
                s_alpha[w][l][0] = __expf(sc.x - m.x);
                s_alpha[w][l][1] = __expf(sc.y - m.y);
                s_alpha[w][l][2] = __expf(sc.z - m.z);
                s_alpha[w][l][3] = __expf(sc.w - m.w);
                s_src[w][l] = s;
            }
        }
        int e = 0;
        for (; e + 4 <= cl; e += 4) {
            int s0 = s_src[w][e + 0], s1 = s_src[w][e + 1];
            int s2 = s_src[w][e + 2], s3 = s_src[w][e + 3];
            float a0 = s_alpha[w][e + 0][head];
            float a1 = s_alpha[w][e + 1][head];
            float a2 = s_alpha[w][e + 2][head];
            float a3 = s_alpha[w][e + 3][head];
            float4 v0 = *(const float4*)(h + (size_t)s0 * 256 + l * 4);
            float4 v1 = *(const float4*)(h + (size_t)s1 * 256 + l * 4);
            float4 v2 = *(const float4*)(h + (size_t)s2 * 256 + l * 4);
            float4 v3 = *(const float4*)(h + (size_t)s3 * 256 + l * 4);
            acc.x = fmaf(a0, v0.x, acc.x); acc.y = fmaf(a0, v0.y, acc.y);
            acc.z = fmaf(a0, v0.z, acc.z); acc.w = fmaf(a0, v0.w, acc.w);
            acc.x = fmaf(a1, v1.x, acc.x); acc.y = fmaf(a1, v1.y, acc.y);
            acc.z = fmaf(a1, v1.z, acc.z); acc.w = fmaf(a1, v1.w, acc.w);
            acc.x = fmaf(a2, v2.x, acc.x); acc.y = fmaf(a2, v2.y, acc.y);
            acc.z = fmaf(a2, v2.z, acc.z); acc.w = fmaf(a2, v2.w, acc.w);
            acc.x = fmaf(a3, v3.x, acc.x); acc.y = fmaf(a3, v3.y, acc.y);
            acc.z = fmaf(a3, v3.z, acc.z); acc.w = fmaf(a3, v3.w, acc.w);
        }
        for (; e < cl; ++e) {
            int s0 = s_src[w][e];
            float a0 = s_alpha[w][e][head];
            float4 v0 = *(const float4*)(h + (size_t)s0 * 256 + l * 4);
            acc.x = fmaf(a0, v0.x, acc.x); acc.y = fmaf(a0, v0.y, acc.y);
            acc.z = fmaf(a0, v0.z, acc.z); acc.w = fmaf(a0, v0.w, acc.w);
        }
    }
    float4 bv = *(const float4*)(bias + l * 4);
    float4 r = make_float4(acc.x * rc + bv.x, acc.y * rc + bv.y,
                           acc.z * rc + bv.z, acc.w * rc + bv.w);
    if (ACT) {
        r.x = (r.x > 0.f) ? r.x : expm1f(r.x);
        r.y = (r.y > 0.f) ? r.y : expm1f(r.y);
        r.z = (r.z > 0.f) ? r.z : expm1f(r.z);
        r.w = (r.w > 0.f) ? r.w : expm1f(r.w);
    }
    *(float4*)(out + (size_t)n * 256 + l * 4) = r;
}

// ---------------- aggregation H=1 C=128: 1 wave / node, float2 / lane ------
__global__ __launch_bounds__(256) void aggregate_h1_v2(
    const float* __restrict__ h, const float* __restrict__ als,
    const float* __restrict__ ald, const int* __restrict__ offs,
    const int* __restrict__ csr, const float* __restrict__ bias,
    float* __restrict__ out, int Nn) {
    const int tid = threadIdx.x;
    const int w = tid >> 6;
    const int l = tid & 63;
    const int n = blockIdx.x * 4 + w;
    __shared__ float s_alpha[4][64];
    __shared__ int s_src[4][64];
    if (n >= Nn) return;

    const int base = offs[n];
    const int deg = offs[n + 1] - base;
    const float ad_n = ald[n];

    const bool has0 = (l < deg);
    int src0 = 0;
    float sc0 = -1e30f;
    if (has0) {
        src0 = csr[base + l];
        float sc = als[src0] + ad_n;
        sc0 = (sc < 0.f) ? NEG_SLOPE * sc : sc;
    }
    float m = sc0;
    for (int i = l + 64; i < deg; i += 64) {
        int s = csr[base + i];
        float sc = als[s] + ad_n;
        sc = (sc < 0.f) ? NEG_SLOPE * sc : sc;
        m = fmaxf(m, sc);
    }
    m = wave_allred_max(m);

    float ssum = 0.f;
    if (has0) {
        float ex = __expf(sc0 - m);
        s_alpha[w][l] = ex;
        s_src[w][l] = src0;
        ssum = ex;
    }
    for (int i = l + 64; i < deg; i += 64) {
        int s = csr[base + i];
        float sc = als[s] + ad_n;
        sc = (sc < 0.f) ? NEG_SLOPE * sc : sc;
        ssum += __expf(sc - m);
    }
    ssum = wave_allred_sum(ssum);
    const float rc = 1.f / (ssum + EPS_SM);

    float2 acc = make_float2(0.f, 0.f);
    for (int c0 = 0; c0 < deg; c0 += 64) {
        const int cl = min(64, deg - c0);
        if (c0 > 0) {
            if (l < cl) {
                int s = csr[base + c0 + l];
                float sc = als[s] + ad_n;
                sc = (sc < 0.f) ? NEG_SLOPE * sc : sc;
                s_alpha[w][l] = __expf(sc - m);
                s_src[w][l] = s;
            }
        }
        int e = 0;
        for (; e + 4 <= cl; e += 4) {
            int s0 = s_src[w][e + 0], s1 = s_src[w][e + 1];
            int s2 = s_src[w][e + 2], s3 = s_src[w][e + 3];
            float a0 = s_alpha[w][e + 0], a1 = s_alpha[w][e + 1];
            float a2 = s_alpha[w][e + 2], a3 = s_alpha[w][e + 3];
            float2 v0 = *(const float2*)(h + (size_t)s0 * 128 + l * 2);
            float2 v1 = *(const float2*)(h + (size_t)s1 * 128 + l * 2);
            float2 v2 = *(const float2*)(h + (size_t)s2 * 128 + l * 2);
            float2 v3 = *(const float2*)(h + (size_t)s3 * 128 + l * 2);
            acc.x = fmaf(a0, v0.x, acc.x); acc.y = fmaf(a0, v0.y, acc.y);
            acc.x = fmaf(a1, v1.x, acc.x); acc.y = fmaf(a1, v1.y, acc.y);
            acc.x = fmaf(a2, v2.x, acc.x); acc.y = fmaf(a2, v2.y, acc.y);
            acc.x = fmaf(a3, v3.x, acc.x); acc.y = fmaf(a3, v3.y, acc.y);
        }
        for (; e < cl; ++e) {
            int s0 = s_src[w][e];
            float a0 = s_alpha[w][e];
            float2 v0 = *(const float2*)(h + (size_t)s0 * 128 + l * 2);
            acc.x = fmaf(a0, v0.x, acc.x); acc.y = fmaf(a0, v0.y, acc.y);
        }
    }
    float2 r = make_float2(acc.x * rc + bias[l * 2],
                           acc.y * rc + bias[l * 2 + 1]);
    *(float2*)(out + (size_t)n * 128 + l * 2) = r;
}

// ---------------------------------------------------------------------------
extern "C" void kernel_launch(void* const* d_in, const int* in_sizes, int n_in,
                              void* d_out, int out_size, void* d_ws,
                              size_t ws_size, hipStream_t stream) {
    const float* x   = (const float*)d_in[0];
    const int*   ei  = (const int*)d_in[1];
    const float* W1  = (const float*)d_in[2];
    const float* as1 = (const float*)d_in[3];
    const float* ad1 = (const float*)d_in[4];
    const float* b1  = (const float*)d_in[5];
    const float* W2  = (const float*)d_in[6];
    const float* as2 = (const float*)d_in[7];
    const float* ad2 = (const float*)d_in[8];
    const float* b2  = (const float*)d_in[9];
    const float* W3  = (const float*)d_in[10];
    const float* as3 = (const float*)d_in[11];
    const float* ad3 = (const float*)d_in[12];
    const float* b3  = (const float*)d_in[13];

    const int Nn = in_sizes[0] / 256;   // 50000 nodes
    const int E  = in_sizes[1] / 2;     // 800000 edges
    const int ET = E + Nn;              // + self loops

    // workspace carve
    char* p = (char*)d_ws;
    float* bufA = (float*)p; p += (size_t)Nn * 256 * 4;
    float* bufB = (float*)p; p += (size_t)Nn * 256 * 4;
    float* als  = (float*)p; p += (size_t)Nn * 4 * 4;
    float* ald  = (float*)p; p += (size_t)Nn * 4 * 4;
    int* cnt  = (int*)p; p += (size_t)Nn * 4;
    int* fil  = (int*)p; p += (size_t)Nn * 4;
    int* offs = (int*)p; p += (size_t)(Nn + 1) * 4;
    int* bsums = (int*)p; p += 256 * 4;
    int* csr  = (int*)p; p += (size_t)ET * 4;

    // --- CSR build ---
    hipMemsetAsync(cnt, 0, (size_t)2 * Nn * sizeof(int), stream);  // cnt + fil
    int nbE = (ET + 255) / 256;
    hist_kernel<<<nbE, 256, 0, stream>>>(ei, E, Nn, cnt);
    int nbS = (Nn + 1 + 1023) / 1024;
    scan_block<<<nbS, 1024, 0, stream>>>(cnt, Nn, offs, Nn + 1, bsums);
    scan_sums<<<1, 64, 0, stream>>>(bsums, nbS);
    scan_add<<<nbS, 1024, 0, stream>>>(offs, Nn + 1, bsums);
    fill_csr<<<nbE, 256, 0, stream>>>(ei, E, Nn, offs, fil, csr);

    const int gm = (Nn + 127) / 128;        // 391
    const int ga = (Nn + 3) / 4;            // 12500

    // --- layer 1: 256 -> 256, H=4, C=64, ELU ---
    gemm_f32_128<<<dim3(2, gm), 256, 0, stream>>>(x, W1, bufA, Nn, 256, 256);
    al_kernel<4, 64><<<Nn, 64, 0, stream>>>(bufA, as1, ad1, als, ald);
    aggregate_h4_v2<true><<<ga, 256, 0, stream>>>(
        bufA, (const float4*)als, (const float4*)ald, offs, csr, b1, bufB, Nn);

    // --- layer 2: 256 -> 256, H=4, C=64, ELU ---
    gemm_f32_128<<<dim3(2, gm), 256, 0, stream>>>(bufB, W2, bufA, Nn, 256, 256);
    al_kernel<4, 64><<<Nn, 64, 0, stream>>>(bufA, as2, ad2, als, ald);
    aggregate_h4_v2<true><<<ga, 256, 0, stream>>>(
        bufA, (const float4*)als, (const float4*)ald, offs, csr, b2, bufB, Nn);

    // --- layer 3: 256 -> 128, H=1, C=128, no act ---
    gemm_f32_128<<<dim3(1, gm), 256, 0, stream>>>(bufB, W3, bufA, Nn, 128, 256);
    al_kernel<1, 128><<<Nn, 64, 0, stream>>>(bufA, as3, ad3, als, ald);
    aggregate_h1_v2<<<ga, 256, 0, stream>>>(
        bufA, als, ald, offs, csr, b3, (float*)d_out, Nn);
}

// Round 4
// 644.814 us; speedup vs baseline: 1.4000x; 1.3011x over previous
//
#include <hip/hip_runtime.h>
#include <hip/hip_bf16.h>
#include <math.h>

// ---------------------------------------------------------------------------
// GAT 3-layer forward.
// R4: GEMM moved to MFMA via split-bf16 (a = hi + lo truncated bf16;
//     A@B ~= AhBh + AhBl + AlBh, f32 accumulate -> ~f32 precision at 3x bf16
//     MFMA cost). W pre-transposed+split per layer. A converted in staging.
//     al_kernel vectorized. Aggregation unchanged (L3-stream-bound).
// ---------------------------------------------------------------------------

#define NEG_SLOPE 0.2f
#define EPS_SM 1e-16f

typedef __bf16 bf16x8 __attribute__((ext_vector_type(8)));
typedef float f32x4 __attribute__((ext_vector_type(4)));

__device__ __forceinline__ float wave_allred_sum(float v) {
#pragma unroll
    for (int o = 32; o > 0; o >>= 1) v += __shfl_xor(v, o, 64);
    return v;
}
__device__ __forceinline__ float wave_allred_max(float v) {
#pragma unroll
    for (int o = 32; o > 0; o >>= 1) v = fmaxf(v, __shfl_xor(v, o, 64));
    return v;
}
__device__ __forceinline__ float4 lrelu4(float4 v) {
    v.x = (v.x < 0.f) ? NEG_SLOPE * v.x : v.x;
    v.y = (v.y < 0.f) ? NEG_SLOPE * v.y : v.y;
    v.z = (v.z < 0.f) ? NEG_SLOPE * v.z : v.z;
    v.w = (v.w < 0.f) ? NEG_SLOPE * v.w : v.w;
    return v;
}

// ---------------- CSR build ----------------
__global__ void hist_kernel(const int* __restrict__ ei, int E, int N,
                            int* __restrict__ cnt) {
    int e = blockIdx.x * 256 + threadIdx.x;
    int ET = E + N;
    if (e >= ET) return;
    int dst = (e < E) ? ei[E + e] : (e - E);
    atomicAdd(&cnt[dst], 1);
}

__global__ void scan_block(const int* __restrict__ cnt, int n_cnt,
                           int* __restrict__ offs, int n_off,
                           int* __restrict__ bsums) {
    __shared__ int buf[1024];
    int gid = blockIdx.x * 1024 + threadIdx.x;
    int v = (gid < n_cnt) ? cnt[gid] : 0;
    buf[threadIdx.x] = v;
    __syncthreads();
#pragma unroll
    for (int off = 1; off < 1024; off <<= 1) {
        int t = (threadIdx.x >= off) ? buf[threadIdx.x - off] : 0;
        __syncthreads();
        buf[threadIdx.x] += t;
        __syncthreads();
    }
    if (gid < n_off) offs[gid] = buf[threadIdx.x] - v;
    if (threadIdx.x == 1023) bsums[blockIdx.x] = buf[1023];
}

__global__ void scan_sums(int* __restrict__ bsums, int nb) {
    if (threadIdx.x == 0 && blockIdx.x == 0) {
        int run = 0;
        for (int i = 0; i < nb; ++i) { int t = bsums[i]; bsums[i] = run; run += t; }
    }
}

__global__ void scan_add(int* __restrict__ offs, int n_off,
                         const int* __restrict__ bsums) {
    int gid = blockIdx.x * 1024 + threadIdx.x;
    if (gid < n_off) offs[gid] += bsums[blockIdx.x];
}

__global__ void fill_csr(const int* __restrict__ ei, int E, int N,
                         const int* __restrict__ offs, int* __restrict__ fil,
                         int* __restrict__ csr) {
    int e = blockIdx.x * 256 + threadIdx.x;
    int ET = E + N;
    if (e >= ET) return;
    int src, dst;
    if (e < E) { src = ei[e]; dst = ei[E + e]; }
    else       { src = dst = e - E; }
    int pos = offs[dst] + atomicAdd(&fil[dst], 1);
    csr[pos] = src;
}

// ---------------- W transpose + hi/lo bf16 split (tiny, per layer) ---------
__global__ void wsplit_t(const float* __restrict__ W, int K, int N,
                         unsigned short* __restrict__ hi,
                         unsigned short* __restrict__ lo) {
    int idx = blockIdx.x * 256 + threadIdx.x;  // over N*K, k-fast
    if (idx >= N * K) return;
    int n = idx / K, k = idx - n * K;
    float v = W[(size_t)k * N + n];
    unsigned u = __float_as_uint(v);
    float d = v - __uint_as_float(u & 0xffff0000u);
    hi[idx] = (unsigned short)(u >> 16);
    lo[idx] = (unsigned short)(__float_as_uint(d) >> 16);
}

// ---------------- split-bf16 MFMA GEMM: C[M,N] = A[M,K] @ B[K,N] -----------
// A: f32 [M,K] (converted in staging). Bt_hi/Bt_lo: bf16 bits [N,K].
// BM=128 BN=128 BK=32; 4 waves 2x2; wave tile 64x64 = 4x4 16x16x32 MFMA.
__global__ __launch_bounds__(256) void gemm_mfma_split(
    const float* __restrict__ A, const unsigned short* __restrict__ Bt_hi,
    const unsigned short* __restrict__ Bt_lo, float* __restrict__ C,
    int M, int N, int K) {
    __shared__ unsigned short Ah[128][40], Al[128][40];  // [m][k], +8 pad
    __shared__ unsigned short Bh[128][40], Bl[128][40];  // [n][k], +8 pad
    const int bm = blockIdx.y * 128, bn = blockIdx.x * 128;
    const int tid = threadIdx.x;
    const int w = tid >> 6, lane = tid & 63;
    const int wm = (w >> 1) * 64, wn = (w & 1) * 64;
    const int l16 = lane & 15, q = lane >> 4;
    const int kq = q * 8;
    const int sr = tid >> 1;          // staging row 0..127
    const int sk = (tid & 1) * 16;    // staging k-offset 0/16

    f32x4 acc[4][4];
#pragma unroll
    for (int i = 0; i < 4; ++i)
#pragma unroll
        for (int j = 0; j < 4; ++j) acc[i][j] = (f32x4){0.f, 0.f, 0.f, 0.f};

    for (int k0 = 0; k0 < K; k0 += 32) {
        // ---- stage A (f32 -> hi/lo bf16 via truncation) ----
        {
            int row = bm + sr;
            float4 v0, v1, v2, v3;
            if (row < M) {
                const float4* ap = (const float4*)(A + (size_t)row * K + k0 + sk);
                v0 = ap[0]; v1 = ap[1]; v2 = ap[2]; v3 = ap[3];
            } else {
                v0 = v1 = v2 = v3 = make_float4(0.f, 0.f, 0.f, 0.f);
            }
            float vf[16] = {v0.x, v0.y, v0.z, v0.w, v1.x, v1.y, v1.z, v1.w,
                            v2.x, v2.y, v2.z, v2.w, v3.x, v3.y, v3.z, v3.w};
            unsigned hi[8], lo[8];
#pragma unroll
            for (int i = 0; i < 8; ++i) {
                unsigned u0 = __float_as_uint(vf[2 * i]);
                unsigned u1 = __float_as_uint(vf[2 * i + 1]);
                hi[i] = (u0 >> 16) | (u1 & 0xffff0000u);
                float d0 = vf[2 * i]     - __uint_as_float(u0 & 0xffff0000u);
                float d1 = vf[2 * i + 1] - __uint_as_float(u1 & 0xffff0000u);
                lo[i] = (__float_as_uint(d0) >> 16) |
                        (__float_as_uint(d1) & 0xffff0000u);
            }
            *(uint4*)&Ah[sr][sk]     = make_uint4(hi[0], hi[1], hi[2], hi[3]);
            *(uint4*)&Ah[sr][sk + 8] = make_uint4(hi[4], hi[5], hi[6], hi[7]);
            *(uint4*)&Al[sr][sk]     = make_uint4(lo[0], lo[1], lo[2], lo[3]);
            *(uint4*)&Al[sr][sk + 8] = make_uint4(lo[4], lo[5], lo[6], lo[7]);
        }
        // ---- stage B (pre-split bf16, straight copy) ----
        {
            const uint4* bph = (const uint4*)(Bt_hi + (size_t)(bn + sr) * K + k0 + sk);
            const uint4* bpl = (const uint4*)(Bt_lo + (size_t)(bn + sr) * K + k0 + sk);
            *(uint4*)&Bh[sr][sk]     = bph[0];
            *(uint4*)&Bh[sr][sk + 8] = bph[1];
            *(uint4*)&Bl[sr][sk]     = bpl[0];
            *(uint4*)&Bl[sr][sk + 8] = bpl[1];
        }
        __syncthreads();
        bf16x8 aH[4], aL[4], bH[4], bL[4];
#pragma unroll
        for (int t = 0; t < 4; ++t) {
            aH[t] = *(const bf16x8*)&Ah[wm + t * 16 + l16][kq];
            aL[t] = *(const bf16x8*)&Al[wm + t * 16 + l16][kq];
            bH[t] = *(const bf16x8*)&Bh[wn + t * 16 + l16][kq];
            bL[t] = *(const bf16x8*)&Bl[wn + t * 16 + l16][kq];
        }
#pragma unroll
        for (int i = 0; i < 4; ++i)
#pragma unroll
            for (int j = 0; j < 4; ++j) {
                acc[i][j] = __builtin_amdgcn_mfma_f32_16x16x32_bf16(
                    aH[i], bH[j], acc[i][j], 0, 0, 0);
                acc[i][j] = __builtin_amdgcn_mfma_f32_16x16x32_bf16(
                    aH[i], bL[j], acc[i][j], 0, 0, 0);
                acc[i][j] = __builtin_amdgcn_mfma_f32_16x16x32_bf16(
                    aL[i], bH[j], acc[i][j], 0, 0, 0);
            }
        __syncthreads();
    }
    // epilogue: C/D layout col = lane&15, row = q*4 + reg
#pragma unroll
    for (int i = 0; i < 4; ++i) {
#pragma unroll
        for (int r = 0; r < 4; ++r) {
            int row = bm + wm + i * 16 + q * 4 + r;
            if (row < M) {
                float* cp = C + (size_t)row * N + bn + wn + l16;
                cp[0]  = acc[i][0][r];
                cp[16] = acc[i][1][r];
                cp[32] = acc[i][2][r];
                cp[48] = acc[i][3][r];
            }
        }
    }
}

// ---------------- attention logits (vectorized) ----------------
__global__ __launch_bounds__(256) void al4_kernel(
    const float* __restrict__ h, const float* __restrict__ a_s,
    const float* __restrict__ a_d, float* __restrict__ als,
    float* __restrict__ ald, int Nn) {
    const int w = threadIdx.x >> 6, l = threadIdx.x & 63;
    const int n = blockIdx.x * 4 + w;
    if (n >= Nn) return;
    float4 v  = *(const float4*)(h + (size_t)n * 256 + l * 4);
    float4 s4 = *(const float4*)(a_s + l * 4);
    float4 d4 = *(const float4*)(a_d + l * 4);
    float ps = v.x * s4.x + v.y * s4.y + v.z * s4.z + v.w * s4.w;
    float pd = v.x * d4.x + v.y * d4.y + v.z * d4.z + v.w * d4.w;
#pragma unroll
    for (int o = 1; o < 16; o <<= 1) {
        ps += __shfl_xor(ps, o, 64);
        pd += __shfl_xor(pd, o, 64);
    }
    if ((l & 15) == 0) {
        als[n * 4 + (l >> 4)] = ps;
        ald[n * 4 + (l >> 4)] = pd;
    }
}

__global__ __launch_bounds__(256) void al1_kernel(
    const float* __restrict__ h, const float* __restrict__ a_s,
    const float* __restrict__ a_d, float* __restrict__ als,
    float* __restrict__ ald, int Nn) {
    const int w = threadIdx.x >> 6, l = threadIdx.x & 63;
    const int n = blockIdx.x * 4 + w;
    if (n >= Nn) return;
    float2 v  = *(const float2*)(h + (size_t)n * 128 + l * 2);
    float2 s2 = *(const float2*)(a_s + l * 2);
    float2 d2 = *(const float2*)(a_d + l * 2);
    float ps = v.x * s2.x + v.y * s2.y;
    float pd = v.x * d2.x + v.y * d2.y;
    ps = wave_allred_sum(ps);
    pd = wave_allred_sum(pd);
    if (l == 0) { als[n] = ps; ald[n] = pd; }
}

// ---------------- aggregation H=4 C=64: 1 wave / node, float4 / lane -------
template <bool ACT>
__global__ __launch_bounds__(256) void aggregate_h4_v2(
    const float* __restrict__ h, const float4* __restrict__ als4,
    const float4* __restrict__ ald4, const int* __restrict__ offs,
    const int* __restrict__ csr, const float* __restrict__ bias,
    float* __restrict__ out, int Nn) {
    const int tid = threadIdx.x;
    const int w = tid >> 6;
    const int l = tid & 63;
    const int n = blockIdx.x * 4 + w;
    __shared__ float s_alpha[4][64][4];
    __shared__ int s_src[4][64];
    if (n >= Nn) return;

    const int base = offs[n];
    const int deg = offs[n + 1] - base;
    const float4 adv = ald4[n];

    const bool has0 = (l < deg);
    int src0 = 0;
    float4 sc0 = make_float4(-1e30f, -1e30f, -1e30f, -1e30f);
    if (has0) {
        src0 = csr[base + l];
        float4 a = als4[src0];
        sc0 = lrelu4(make_float4(a.x + adv.x, a.y + adv.y, a.z + adv.z, a.w + adv.w));
    }
    float4 m = sc0;
    for (int i = l + 64; i < deg; i += 64) {
        int s = csr[base + i];
        float4 a = als4[s];
        float4 sc = lrelu4(make_float4(a.x + adv.x, a.y + adv.y, a.z + adv.z, a.w + adv.w));
        m.x = fmaxf(m.x, sc.x); m.y = fmaxf(m.y, sc.y);
        m.z = fmaxf(m.z, sc.z); m.w = fmaxf(m.w, sc.w);
    }
    m.x = wave_allred_max(m.x); m.y = wave_allred_max(m.y);
    m.z = wave_allred_max(m.z); m.w = wave_allred_max(m.w);

    float4 ssum = make_float4(0.f, 0.f, 0.f, 0.f);
    if (has0) {
        float4 ex = make_float4(__expf(sc0.x - m.x), __expf(sc0.y - m.y),
                                __expf(sc0.z - m.z), __expf(sc0.w - m.w));
        *(float4*)&s_alpha[w][l][0] = ex;
        s_src[w][l] = src0;
        ssum = ex;
    }
    for (int i = l + 64; i < deg; i += 64) {
        int s = csr[base + i];
        float4 a = als4[s];
        float4 sc = lrelu4(make_float4(a.x + adv.x, a.y + adv.y, a.z + adv.z, a.w + adv.w));
        ssum.x += __expf(sc.x - m.x); ssum.y += __expf(sc.y - m.y);
        ssum.z += __expf(sc.z - m.z); ssum.w += __expf(sc.w - m.w);
    }
    ssum.x = wave_allred_sum(ssum.x); ssum.y = wave_allred_sum(ssum.y);
    ssum.z = wave_allred_sum(ssum.z); ssum.w = wave_allred_sum(ssum.w);

    const int head = l >> 4;
    float rc;
    {
        float d = (head == 0) ? ssum.x : (head == 1) ? ssum.y
                 : (head == 2) ? ssum.z : ssum.w;
        rc = 1.f / (d + EPS_SM);
    }

    float4 acc = make_float4(0.f, 0.f, 0.f, 0.f);
    for (int c0 = 0; c0 < deg; c0 += 64) {
        const int cl = min(64, deg - c0);
        if (c0 > 0) {
            if (l < cl) {
                int s = csr[base + c0 + l];
                float4 a = als4[s];
                float4 sc = lrelu4(make_float4(a.x + adv.x, a.y + adv.y,
                                               a.z + adv.z, a.w + adv.w));
                s_alpha[w][l][0] = __expf(sc.x - m.x);
                s_alpha[w][l][1] = __expf(sc.y - m.y);
                s_alpha[w][l][2] = __expf(sc.z - m.z);
                s_alpha[w][l][3] = __expf(sc.w - m.w);
                s_src[w][l] = s;
            }
        }
        int e = 0;
        for (; e + 4 <= cl; e += 4) {
            int s0 = s_src[w][e + 0], s1 = s_src[w][e + 1];
            int s2 = s_src[w][e + 2], s3 = s_src[w][e + 3];
            float a0 = s_alpha[w][e + 0][head];
            float a1 = s_alpha[w][e + 1][head];
            float a2 = s_alpha[w][e + 2][head];
            float a3 = s_alpha[w][e + 3][head];
            float4 v0 = *(const float4*)(h + (size_t)s0 * 256 + l * 4);
            float4 v1 = *(const float4*)(h + (size_t)s1 * 256 + l * 4);
            float4 v2 = *(const float4*)(h + (size_t)s2 * 256 + l * 4);
            float4 v3 = *(const float4*)(h + (size_t)s3 * 256 + l * 4);
            acc.x = fmaf(a0, v0.x, acc.x); acc.y = fmaf(a0, v0.y, acc.y);
            acc.z = fmaf(a0, v0.z, acc.z); acc.w = fmaf(a0, v0.w, acc.w);
            acc.x = fmaf(a1, v1.x, acc.x); acc.y = fmaf(a1, v1.y, acc.y);
            acc.z = fmaf(a1, v1.z, acc.z); acc.w = fmaf(a1, v1.w, acc.w);
            acc.x = fmaf(a2, v2.x, acc.x); acc.y = fmaf(a2, v2.y, acc.y);
            acc.z = fmaf(a2, v2.z, acc.z); acc.w = fmaf(a2, v2.w, acc.w);
            acc.x = fmaf(a3, v3.x, acc.x); acc.y = fmaf(a3, v3.y, acc.y);
            acc.z = fmaf(a3, v3.z, acc.z); acc.w = fmaf(a3, v3.w, acc.w);
        }
        for (; e < cl; ++e) {
            int s0 = s_src[w][e];
            float a0 = s_alpha[w][e][head];
            float4 v0 = *(const float4*)(h + (size_t)s0 * 256 + l * 4);
            acc.x = fmaf(a0, v0.x, acc.x); acc.y = fmaf(a0, v0.y, acc.y);
            acc.z = fmaf(a0, v0.z, acc.z); acc.w = fmaf(a0, v0.w, acc.w);
        }
    }
    float4 bv = *(const float4*)(bias + l * 4);
    float4 r = make_float4(acc.x * rc + bv.x, acc.y * rc + bv.y,
                           acc.z * rc + bv.z, acc.w * rc + bv.w);
    if (ACT) {
        r.x = (r.x > 0.f) ? r.x : expm1f(r.x);
        r.y = (r.y > 0.f) ? r.y : expm1f(r.y);
        r.z = (r.z > 0.f) ? r.z : expm1f(r.z);
        r.w = (r.w > 0.f) ? r.w : expm1f(r.w);
    }
    *(float4*)(out + (size_t)n * 256 + l * 4) = r;
}

// ---------------- aggregation H=1 C=128 ----------------
__global__ __launch_bounds__(256) void aggregate_h1_v2(
    const float* __restrict__ h, const float* __restrict__ als,
    const float* __restrict__ ald, const int* __restrict__ offs,
    const int* __restrict__ csr, const float* __restrict__ bias,
    float* __restrict__ out, int Nn) {
    const int tid = threadIdx.x;
    const int w = tid >> 6;
    const int l = tid & 63;
    const int n = blockIdx.x * 4 + w;
    __shared__ float s_alpha[4][64];
    __shared__ int s_src[4][64];
    if (n >= Nn) return;

    const int base = offs[n];
    const int deg = offs[n + 1] - base;
    const float ad_n = ald[n];

    const bool has0 = (l < deg);
    int src0 = 0;
    float sc0 = -1e30f;
    if (has0) {
        src0 = csr[base + l];
        float sc = als[src0] + ad_n;
        sc0 = (sc < 0.f) ? NEG_SLOPE * sc : sc;
    }
    float m = sc0;
    for (int i = l + 64; i < deg; i += 64) {
        int s = csr[base + i];
        float sc = als[s] + ad_n;
        sc = (sc < 0.f) ? NEG_SLOPE * sc : sc;
        m = fmaxf(m, sc);
    }
    m = wave_allred_max(m);

    float ssum = 0.f;
    if (has0) {
        float ex = __expf(sc0 - m);
        s_alpha[w][l] = ex;
        s_src[w][l] = src0;
        ssum = ex;
    }
    for (int i = l + 64; i < deg; i += 64) {
        int s = csr[base + i];
        float sc = als[s] + ad_n;
        sc = (sc < 0.f) ? NEG_SLOPE * sc : sc;
        ssum += __expf(sc - m);
    }
    ssum = wave_allred_sum(ssum);
    const float rc = 1.f / (ssum + EPS_SM);

    float2 acc = make_float2(0.f, 0.f);
    for (int c0 = 0; c0 < deg; c0 += 64) {
        const int cl = min(64, deg - c0);
        if (c0 > 0) {
            if (l < cl) {
                int s = csr[base + c0 + l];
                float sc = als[s] + ad_n;
                sc = (sc < 0.f) ? NEG_SLOPE * sc : sc;
                s_alpha[w][l] = __expf(sc - m);
                s_src[w][l] = s;
            }
        }
        int e = 0;
        for (; e + 4 <= cl; e += 4) {
            int s0 = s_src[w][e + 0], s1 = s_src[w][e + 1];
            int s2 = s_src[w][e + 2], s3 = s_src[w][e + 3];
            float a0 = s_alpha[w][e + 0], a1 = s_alpha[w][e + 1];
            float a2 = s_alpha[w][e + 2], a3 = s_alpha[w][e + 3];
            float2 v0 = *(const float2*)(h + (size_t)s0 * 128 + l * 2);
            float2 v1 = *(const float2*)(h + (size_t)s1 * 128 + l * 2);
            float2 v2 = *(const float2*)(h + (size_t)s2 * 128 + l * 2);
            float2 v3 = *(const float2*)(h + (size_t)s3 * 128 + l * 2);
            acc.x = fmaf(a0, v0.x, acc.x); acc.y = fmaf(a0, v0.y, acc.y);
            acc.x = fmaf(a1, v1.x, acc.x); acc.y = fmaf(a1, v1.y, acc.y);
            acc.x = fmaf(a2, v2.x, acc.x); acc.y = fmaf(a2, v2.y, acc.y);
            acc.x = fmaf(a3, v3.x, acc.x); acc.y = fmaf(a3, v3.y, acc.y);
        }
        for (; e < cl; ++e) {
            int s0 = s_src[w][e];
            float a0 = s_alpha[w][e];
            float2 v0 = *(const float2*)(h + (size_t)s0 * 128 + l * 2);
            acc.x = fmaf(a0, v0.x, acc.x); acc.y = fmaf(a0, v0.y, acc.y);
        }
    }
    float2 r = make_float2(acc.x * rc + bias[l * 2],
                           acc.y * rc + bias[l * 2 + 1]);
    *(float2*)(out + (size_t)n * 128 + l * 2) = r;
}

// ---------------------------------------------------------------------------
extern "C" void kernel_launch(void* const* d_in, const int* in_sizes, int n_in,
                              void* d_out, int out_size, void* d_ws,
                              size_t ws_size, hipStream_t stream) {
    const float* x   = (const float*)d_in[0];
    const int*   ei  = (const int*)d_in[1];
    const float* W1  = (const float*)d_in[2];
    const float* as1 = (const float*)d_in[3];
    const float* ad1 = (const float*)d_in[4];
    const float* b1  = (const float*)d_in[5];
    const float* W2  = (const float*)d_in[6];
    const float* as2 = (const float*)d_in[7];
    const float* ad2 = (const float*)d_in[8];
    const float* b2  = (const float*)d_in[9];
    const float* W3  = (const float*)d_in[10];
    const float* as3 = (const float*)d_in[11];
    const float* ad3 = (const float*)d_in[12];
    const float* b3  = (const float*)d_in[13];

    const int Nn = in_sizes[0] / 256;   // 50000 nodes
    const int E  = in_sizes[1] / 2;     // 800000 edges
    const int ET = E + Nn;

    // workspace carve
    char* p = (char*)d_ws;
    float* bufA = (float*)p; p += (size_t)Nn * 256 * 4;
    float* bufB = (float*)p; p += (size_t)Nn * 256 * 4;
    float* als  = (float*)p; p += (size_t)Nn * 4 * 4;
    float* ald  = (float*)p; p += (size_t)Nn * 4 * 4;
    int* cnt  = (int*)p; p += (size_t)Nn * 4;
    int* fil  = (int*)p; p += (size_t)Nn * 4;
    int* offs = (int*)p; p += (size_t)(Nn + 1) * 4;
    int* bsums = (int*)p; p += 256 * 4;
    int* csr  = (int*)p; p += (size_t)ET * 4;
    p = (char*)(((uintptr_t)p + 15) & ~(uintptr_t)15);
    unsigned short* wt1h = (unsigned short*)p; p += 256 * 256 * 2;
    unsigned short* wt1l = (unsigned short*)p; p += 256 * 256 * 2;
    unsigned short* wt2h = (unsigned short*)p; p += 256 * 256 * 2;
    unsigned short* wt2l = (unsigned short*)p; p += 256 * 256 * 2;
    unsigned short* wt3h = (unsigned short*)p; p += 128 * 256 * 2;
    unsigned short* wt3l = (unsigned short*)p; p += 128 * 256 * 2;

    // --- CSR build + W splits ---
    hipMemsetAsync(cnt, 0, (size_t)2 * Nn * sizeof(int), stream);
    int nbE = (ET + 255) / 256;
    hist_kernel<<<nbE, 256, 0, stream>>>(ei, E, Nn, cnt);
    wsplit_t<<<(256 * 256 + 255) / 256, 256, 0, stream>>>(W1, 256, 256, wt1h, wt1l);
    wsplit_t<<<(256 * 256 + 255) / 256, 256, 0, stream>>>(W2, 256, 256, wt2h, wt2l);
    wsplit_t<<<(128 * 256 + 255) / 256, 256, 0, stream>>>(W3, 256, 128, wt3h, wt3l);
    int nbS = (Nn + 1 + 1023) / 1024;
    scan_block<<<nbS, 1024, 0, stream>>>(cnt, Nn, offs, Nn + 1, bsums);
    scan_sums<<<1, 64, 0, stream>>>(bsums, nbS);
    scan_add<<<nbS, 1024, 0, stream>>>(offs, Nn + 1, bsums);
    fill_csr<<<nbE, 256, 0, stream>>>(ei, E, Nn, offs, fil, csr);

    const int gm = (Nn + 127) / 128;   // 391
    const int ga = (Nn + 3) / 4;       // 12500

    // --- layer 1: 256 -> 256, H=4, C=64, ELU ---
    gemm_mfma_split<<<dim3(2, gm), 256, 0, stream>>>(x, wt1h, wt1l, bufA, Nn, 256, 256);
    al4_kernel<<<ga, 256, 0, stream>>>(bufA, as1, ad1, als, ald, Nn);
    aggregate_h4_v2<true><<<ga, 256, 0, stream>>>(
        bufA, (const float4*)als, (const float4*)ald, offs, csr, b1, bufB, Nn);

    // --- layer 2: 256 -> 256, H=4, C=64, ELU ---
    gemm_mfma_split<<<dim3(2, gm), 256, 0, stream>>>(bufB, wt2h, wt2l, bufA, Nn, 256, 256);
    al4_kernel<<<ga, 256, 0, stream>>>(bufA, as2, ad2, als, ald, Nn);
    aggregate_h4_v2<true><<<ga, 256, 0, stream>>>(
        bufA, (const float4*)als, (const float4*)ald, offs, csr, b2, bufB, Nn);

    // --- layer 3: 256 -> 128, H=1, C=128, no act ---
    gemm_mfma_split<<<dim3(1, gm), 256, 0, stream>>>(bufB, wt3h, wt3l, bufA, Nn, 128, 256);
    al1_kernel<<<ga, 256, 0, stream>>>(bufA, as3, ad3, als, ald, Nn);
    aggregate_h1_v2<<<ga, 256, 0, stream>>>(
        bufA, als, ald, offs, csr, b3, (float*)d_out, Nn);
}